// Round 6
// baseline (269.854 us; speedup 1.0000x reference)
//
#include <hip/hip_runtime.h>
#include <hip/hip_fp16.h>
#include <cstdint>
#include <cstddef>

#define Bb 32
#define Ss 2048
#define Ee 1024
#define Qq 1024
#define Aa 512

typedef _Float16 half8 __attribute__((ext_vector_type(8)));
typedef float f32x4 __attribute__((ext_vector_type(4)));

// ---- workspace byte offsets ----
#define WS_PROJQ 0u          // 32*512 f32      = 65536 B
#define WS_MPART 65536u      // 32*64 f32       = 8192 B
#define WS_LPART 73728u      // 32*64 f32       = 8192 B
#define WS_CTXP  81920u      // 32*64*512 f32   = 4194304 B
#define WS_WWS   4276224u    // 1024*512 f16    = 1048576 B   (total ~5.1 MB)

__device__ __forceinline__ float fast_tanh(float x) {
  float e = __expf(2.0f * x);
  return 1.0f - __fdividef(2.0f, e + 1.0f);
}

// ---- W_in fp32 [E][A] -> fp16 tiled [kt][ks][a][8]  (1 MB, L2-resident)
__global__ void k_convw(const float* __restrict__ win, _Float16* __restrict__ wws) {
  int gid = blockIdx.x * 256 + threadIdx.x;
  int a  = gid & 511;
  int ks = (gid >> 9) & 3;
  int kt = gid >> 11;
  int k0 = kt * 32 + ks * 8;
  half8 v;
  #pragma unroll
  for (int j = 0; j < 8; ++j) v[j] = (_Float16)win[(size_t)(k0 + j) * Aa + a];
  *(half8*)(wws + ((size_t)kt * 16384 + (size_t)ks * 4096 + (size_t)a * 8)) = v;
}

// ---- proj_q[b][a]
__global__ void k_projq(const float* __restrict__ query, const float* __restrict__ wq,
                        float* __restrict__ projq) {
  __shared__ float red[256];
  int b  = blockIdx.y;
  int al = threadIdx.x & 63;
  int eq = threadIdx.x >> 6;
  int a  = blockIdx.x * 64 + al;
  const float* q = query + (size_t)b * Qq;
  float s = 0.f;
  int e0 = eq * 256;
  #pragma unroll 4
  for (int e = e0; e < e0 + 256; ++e)
    s += q[e] * wq[(size_t)e * Aa + a];
  red[threadIdx.x] = s;
  __syncthreads();
  if (eq == 0)
    projq[(size_t)b * Aa + a] = red[al] + red[al + 64] + red[al + 128] + red[al + 192];
}

// ---- main: 32-row s-chunk x 512 cols, 256 threads, NO barriers / NO LDS in K-loop.
// A fragments loaded directly from global (f32, wave-coalesced 16rows x 128B; the 4
// waves of a block read identical addresses -> L1 broadcast). B direct from L2-resident
// tiled wws (R2-verified indexing). Waves self-pace; compiler free to pipeline loads.
__global__ __launch_bounds__(256, 3)
void k_main(const float* __restrict__ inp, const _Float16* __restrict__ wws,
            const float* __restrict__ projq, const float* __restrict__ watt,
            float* __restrict__ mpart, float* __restrict__ lpart,
            float* __restrict__ ctxp)
{
  __shared__ float pq_s[512];
  __shared__ float wa_s[512];
  __shared__ float sc4[32][4];
  __shared__ float pbuf[32];

  const int tid = threadIdx.x;
  const int l   = tid & 63;
  const int w   = tid >> 6;        // wave = col-slice 0..3
  const int lr  = l & 15;
  const int kb  = l >> 4;          // k-slot 0..3
  const int b   = blockIdx.y;
  const int ch  = blockIdx.x;      // s-chunk of 32 rows, 0..63

  pq_s[tid]       = projq[(size_t)b * Aa + tid];
  pq_s[tid + 256] = projq[(size_t)b * Aa + tid + 256];
  wa_s[tid]       = watt[tid];
  wa_s[tid + 256] = watt[tid + 256];
  __syncthreads();                 // the ONLY pre-epilogue barrier

  // per-lane A sources: row lr (m=0) and row lr+16 (m=1), k-slot kb
  const float* a0 = inp + ((size_t)(b * Ss + ch * 32 + lr     )) * Ee + kb * 8;
  const float* a1 = inp + ((size_t)(b * Ss + ch * 32 + lr + 16)) * Ee + kb * 8;
  // B per-lane base: byte offset (kb*512 + w*128 + lr)*16, then +kt*32768 +n*256
  const char* bptr = (const char*)wws + (size_t)((kb * 512 + w * 128 + lr) * 16);

  f32x4 acc[2][8];
  #pragma unroll
  for (int m = 0; m < 2; ++m)
    #pragma unroll
    for (int n = 0; n < 8; ++n) acc[m][n] = (f32x4){0.f, 0.f, 0.f, 0.f};

  #pragma unroll 2
  for (int kt = 0; kt < 32; ++kt) {
    // A: 2 rows x 8 f32 (4x float4, fully coalesced across the wave)
    const float* pa0 = a0 + (size_t)kt * 32;
    const float* pa1 = a1 + (size_t)kt * 32;
    float4 x0 = *(const float4*)(pa0);
    float4 x1 = *(const float4*)(pa0 + 4);
    float4 y0 = *(const float4*)(pa1);
    float4 y1 = *(const float4*)(pa1 + 4);

    // B: 8 x 16B from L2-resident tiled W
    const char* bk = bptr + (size_t)kt * 32768;
    half8 bf0 = *(const half8*)(bk);
    half8 bf1 = *(const half8*)(bk + 256);
    half8 bf2 = *(const half8*)(bk + 512);
    half8 bf3 = *(const half8*)(bk + 768);
    half8 bf4 = *(const half8*)(bk + 1024);
    half8 bf5 = *(const half8*)(bk + 1280);
    half8 bf6 = *(const half8*)(bk + 1536);
    half8 bf7 = *(const half8*)(bk + 1792);

    half8 af0, af1;
    af0[0]=(_Float16)x0.x; af0[1]=(_Float16)x0.y; af0[2]=(_Float16)x0.z; af0[3]=(_Float16)x0.w;
    af0[4]=(_Float16)x1.x; af0[5]=(_Float16)x1.y; af0[6]=(_Float16)x1.z; af0[7]=(_Float16)x1.w;
    af1[0]=(_Float16)y0.x; af1[1]=(_Float16)y0.y; af1[2]=(_Float16)y0.z; af1[3]=(_Float16)y0.w;
    af1[4]=(_Float16)y1.x; af1[5]=(_Float16)y1.y; af1[6]=(_Float16)y1.z; af1[7]=(_Float16)y1.w;

    acc[0][0] = __builtin_amdgcn_mfma_f32_16x16x32_f16(af0, bf0, acc[0][0], 0, 0, 0);
    acc[1][0] = __builtin_amdgcn_mfma_f32_16x16x32_f16(af1, bf0, acc[1][0], 0, 0, 0);
    acc[0][1] = __builtin_amdgcn_mfma_f32_16x16x32_f16(af0, bf1, acc[0][1], 0, 0, 0);
    acc[1][1] = __builtin_amdgcn_mfma_f32_16x16x32_f16(af1, bf1, acc[1][1], 0, 0, 0);
    acc[0][2] = __builtin_amdgcn_mfma_f32_16x16x32_f16(af0, bf2, acc[0][2], 0, 0, 0);
    acc[1][2] = __builtin_amdgcn_mfma_f32_16x16x32_f16(af1, bf2, acc[1][2], 0, 0, 0);
    acc[0][3] = __builtin_amdgcn_mfma_f32_16x16x32_f16(af0, bf3, acc[0][3], 0, 0, 0);
    acc[1][3] = __builtin_amdgcn_mfma_f32_16x16x32_f16(af1, bf3, acc[1][3], 0, 0, 0);
    acc[0][4] = __builtin_amdgcn_mfma_f32_16x16x32_f16(af0, bf4, acc[0][4], 0, 0, 0);
    acc[1][4] = __builtin_amdgcn_mfma_f32_16x16x32_f16(af1, bf4, acc[1][4], 0, 0, 0);
    acc[0][5] = __builtin_amdgcn_mfma_f32_16x16x32_f16(af0, bf5, acc[0][5], 0, 0, 0);
    acc[1][5] = __builtin_amdgcn_mfma_f32_16x16x32_f16(af1, bf5, acc[1][5], 0, 0, 0);
    acc[0][6] = __builtin_amdgcn_mfma_f32_16x16x32_f16(af0, bf6, acc[0][6], 0, 0, 0);
    acc[1][6] = __builtin_amdgcn_mfma_f32_16x16x32_f16(af1, bf6, acc[1][6], 0, 0, 0);
    acc[0][7] = __builtin_amdgcn_mfma_f32_16x16x32_f16(af0, bf7, acc[0][7], 0, 0, 0);
    acc[1][7] = __builtin_amdgcn_mfma_f32_16x16x32_f16(af1, bf7, acc[1][7], 0, 0, 0);
  }

  // ---------------- epilogue (R5-verified) ----------------
  // C/D: col = lane&15, row(frag) = kb*4 + j ; global row = m*16 + kb*4 + j
  float sp[2][4];
  #pragma unroll
  for (int m = 0; m < 2; ++m)
    #pragma unroll
    for (int j = 0; j < 4; ++j) sp[m][j] = 0.f;

  #pragma unroll
  for (int n = 0; n < 8; ++n) {
    int col = w * 128 + n * 16 + lr;
    float wan = wa_s[col], pqn = pq_s[col];
    #pragma unroll
    for (int m = 0; m < 2; ++m)
      #pragma unroll
      for (int j = 0; j < 4; ++j)
        sp[m][j] += fast_tanh(acc[m][n][j] + pqn) * wan;
  }
  #pragma unroll
  for (int m = 0; m < 2; ++m)
    #pragma unroll
    for (int j = 0; j < 4; ++j) {
      float v = sp[m][j];
      v += __shfl_xor(v, 1);
      v += __shfl_xor(v, 2);
      v += __shfl_xor(v, 4);
      v += __shfl_xor(v, 8);
      sp[m][j] = v;                      // reduced over this wave's 16-col group
    }
  if (lr == 0) {
    #pragma unroll
    for (int m = 0; m < 2; ++m)
      #pragma unroll
      for (int j = 0; j < 4; ++j)
        sc4[m * 16 + kb * 4 + j][w] = sp[m][j];
  }
  __syncthreads();

  const int pi = b * 64 + ch;
  if (tid < 32) {
    float s = sc4[tid][0] + sc4[tid][1] + sc4[tid][2] + sc4[tid][3];
    float mx = s;
    #pragma unroll
    for (int off = 1; off < 32; off <<= 1) mx = fmaxf(mx, __shfl_xor(mx, off));
    float pe = __expf(s - mx);
    float ls = pe;
    #pragma unroll
    for (int off = 1; off < 32; off <<= 1) ls += __shfl_xor(ls, off);
    pbuf[tid] = pe;
    if (tid == 0) { mpart[pi] = mx; lpart[pi] = ls; }
  }
  __syncthreads();

  // ctx partial: sum_s p[s] * proj[s][col]
  float cv[8];
  #pragma unroll
  for (int n = 0; n < 8; ++n) cv[n] = 0.f;
  #pragma unroll
  for (int m = 0; m < 2; ++m)
    #pragma unroll
    for (int j = 0; j < 4; ++j) {
      float pw = pbuf[m * 16 + kb * 4 + j];
      #pragma unroll
      for (int n = 0; n < 8; ++n) cv[n] += pw * acc[m][n][j];
    }
  #pragma unroll
  for (int n = 0; n < 8; ++n) {
    float v = cv[n];
    v += __shfl_xor(v, 16);
    v += __shfl_xor(v, 32);
    cv[n] = v;                           // sum over all 32 rows
  }
  if (l < 16) {
    #pragma unroll
    for (int n = 0; n < 8; ++n)
      ctxp[(size_t)pi * 512 + w * 128 + n * 16 + l] = cv[n];
  }
}

// ---- merge 64 chunk partials per batch (flash-style combine)
__global__ void k_comb(const float* __restrict__ mpart, const float* __restrict__ lpart,
                       const float* __restrict__ ctxp, float* __restrict__ out) {
  int b = blockIdx.x, a = threadIdx.x;
  float Mg = -1e30f;
  #pragma unroll 8
  for (int i = 0; i < 64; ++i) Mg = fmaxf(Mg, mpart[b * 64 + i]);
  float den = 0.f, s = 0.f;
  #pragma unroll 8
  for (int i = 0; i < 64; ++i) {
    float e = __expf(mpart[b * 64 + i] - Mg);
    den += lpart[b * 64 + i] * e;
    s   += ctxp[((size_t)(b * 64 + i)) * 512 + a] * e;
  }
  out[(size_t)b * 512 + a] = s / den;
}

extern "C" void kernel_launch(void* const* d_in, const int* in_sizes, int n_in,
                              void* d_out, int out_size, void* d_ws, size_t ws_size,
                              hipStream_t stream) {
  const float* inputs = (const float*)d_in[0];
  const float* query  = (const float*)d_in[1];
  const float* W_in   = (const float*)d_in[2];
  const float* W_q    = (const float*)d_in[3];
  const float* w_att  = (const float*)d_in[4];
  float* out = (float*)d_out;

  char* ws = (char*)d_ws;
  float*    projq = (float*)(ws + WS_PROJQ);
  float*    mpart = (float*)(ws + WS_MPART);
  float*    lpart = (float*)(ws + WS_LPART);
  float*    ctxp  = (float*)(ws + WS_CTXP);
  _Float16* wws   = (_Float16*)(ws + WS_WWS);

  k_convw<<<256, 256, 0, stream>>>(W_in, wws);
  k_projq<<<dim3(8, 32), 256, 0, stream>>>(query, W_q, projq);
  k_main<<<dim3(64, 32), 256, 0, stream>>>(inputs, wws, projq, w_att, mpart, lpart, ctxp);
  k_comb<<<32, 512, 0, stream>>>(mpart, lpart, ctxp, out);
}

// Round 7
// 193.896 us; speedup vs baseline: 1.3917x; 1.3917x over previous
//
#include <hip/hip_runtime.h>
#include <hip/hip_fp16.h>
#include <cstdint>
#include <cstddef>

#define Bb 32
#define Ss 2048
#define Ee 1024
#define Qq 1024
#define Aa 512

typedef _Float16 half8 __attribute__((ext_vector_type(8)));
typedef _Float16 half4 __attribute__((ext_vector_type(4)));
typedef float f32x4 __attribute__((ext_vector_type(4)));

// ---- workspace byte offsets ----
#define WS_PROJQ 0u          // 32*512 f32      = 65536 B
#define WS_MPART 65536u      // 32*32 f32       = 4096 B
#define WS_LPART 69632u      // 32*32 f32       = 4096 B
#define WS_CTXP  73728u      // 32*32*512 f32   = 2097152 B
#define WS_WWS   2170880u    // 1024*512 f16    = 1048576 B   (total ~3.2 MB)

__device__ __forceinline__ float fast_tanh(float x) {
  float e = __expf(2.0f * x);
  return 1.0f - __fdividef(2.0f, e + 1.0f);
}

// ---- W_in fp32 [E][A] -> fp16 tiled [kt][ks][a][8]  (1 MB, L2-resident)
__global__ void k_convw(const float* __restrict__ win, _Float16* __restrict__ wws) {
  int gid = blockIdx.x * 256 + threadIdx.x;
  int a  = gid & 511;
  int ks = (gid >> 9) & 3;
  int kt = gid >> 11;
  int k0 = kt * 32 + ks * 8;
  half8 v;
  #pragma unroll
  for (int j = 0; j < 8; ++j) v[j] = (_Float16)win[(size_t)(k0 + j) * Aa + a];
  *(half8*)(wws + ((size_t)kt * 16384 + (size_t)ks * 4096 + (size_t)a * 8)) = v;
}

// ---- proj_q[b][a]
__global__ void k_projq(const float* __restrict__ query, const float* __restrict__ wq,
                        float* __restrict__ projq) {
  __shared__ float red[256];
  int b  = blockIdx.y;
  int al = threadIdx.x & 63;
  int eq = threadIdx.x >> 6;
  int a  = blockIdx.x * 64 + al;
  const float* q = query + (size_t)b * Qq;
  float s = 0.f;
  int e0 = eq * 256;
  #pragma unroll 4
  for (int e = e0; e < e0 + 256; ++e)
    s += q[e] * wq[(size_t)e * Aa + a];
  red[threadIdx.x] = s;
  __syncthreads();
  if (eq == 0)
    projq[(size_t)b * Aa + a] = red[al] + red[al + 64] + red[al + 128] + red[al + 192];
}

// ---- main: BM=64 x BN=512, BK=32, 512 threads (2m x 4n waves), m97-style staging.
// B: global_load_lds 16B x4/thread into LDS dbuf (linear layout == tiled wws).
// A: f32->f16 reg-staged, depth-2 pipeline (load kt+2 while writing kt+1).
__global__ __launch_bounds__(512, 4)
void k_main(const float* __restrict__ inp, const _Float16* __restrict__ wws,
            const float* __restrict__ projq, const float* __restrict__ watt,
            float* __restrict__ mpart, float* __restrict__ lpart,
            float* __restrict__ ctxp)
{
  __shared__ __align__(16) _Float16 Alds[2][4 * 64 * 8];    // [p][ks][row64][8]  2x4KB
  __shared__ __align__(16) _Float16 Blds[2][4 * 512 * 8];   // [p][ks][a][8]      2x32KB
  __shared__ float pq_s[512];
  __shared__ float wa_s[512];
  __shared__ float sc4[64][4];
  __shared__ float pbuf[64];
  __shared__ float ctx2[2][512];

  const int tid = threadIdx.x;
  const int l   = tid & 63;
  const int w   = tid >> 6;        // wave 0..7
  const int lr  = l & 15;
  const int kb  = l >> 4;          // k-slot 0..3
  const int wr  = w >> 2;          // m-half 0..1 (rows wr*32..+31)
  const int wc  = w & 3;           // n-slice 0..3 (cols wc*128..+127)
  const int b   = blockIdx.y;
  const int ch  = blockIdx.x;      // s-chunk of 64 rows, 0..31

  pq_s[tid] = projq[(size_t)b * Aa + tid];
  wa_s[tid] = watt[tid];

  // A staging ownership: thread t -> row = t>>3 (0..63), kq = t&7 (4-f32 group)
  const int arow = tid >> 3;
  const int kq   = tid & 7;
  const float* asrc = inp + ((size_t)(b * Ss + ch * 64 + arow)) * Ee + kq * 4;
  // LDS f16 write position: ks = kq>>1, halfpos = (kq&1)*4
  const int awoff = ((kq >> 1) * 64 + arow) * 8 + (kq & 1) * 4;

  // B staging: 4 x 16B per thread, linear
  const char* bsrc0 = (const char*)wws + (size_t)tid * 16;

  f32x4 acc[2][8];
  #pragma unroll
  for (int m = 0; m < 2; ++m)
    #pragma unroll
    for (int n = 0; n < 8; ++n) acc[m][n] = (f32x4){0.f, 0.f, 0.f, 0.f};

  // ---- prologue: stage kt=0 into buf 0; preload A(1) into regs
  {
    float4 x = *(const float4*)(asrc);              // A(0)
    half4 h; h[0]=(_Float16)x.x; h[1]=(_Float16)x.y; h[2]=(_Float16)x.z; h[3]=(_Float16)x.w;
    *(half4*)(Alds[0] + awoff) = h;
    #pragma unroll
    for (int i = 0; i < 4; ++i)
      __builtin_amdgcn_global_load_lds(
        (const __attribute__((address_space(1))) void*)(bsrc0 + i * 8192),
        (__attribute__((address_space(3))) void*)((char*)Blds[0] + tid * 16 + i * 8192),
        16, 0, 0);
  }
  float4 areg = *(const float4*)(asrc + 32);        // A(1)
  __syncthreads();

  int p = 0;
  for (int kt = 0; kt < 32; ++kt) {
    // 1) issue B(kt+1) gloads into buf p^1 (in flight across MFMA phase)
    if (kt < 31) {
      const char* bs = bsrc0 + (size_t)(kt + 1) * 32768;
      #pragma unroll
      for (int i = 0; i < 4; ++i)
        __builtin_amdgcn_global_load_lds(
          (const __attribute__((address_space(1))) void*)(bs + i * 8192),
          (__attribute__((address_space(3))) void*)((char*)Blds[p ^ 1] + tid * 16 + i * 8192),
          16, 0, 0);
    }
    // 2) load A(kt+2) into regs (consumed next iteration -> latency spans barrier)
    const int ktn2 = (kt < 30) ? kt + 2 : 31;
    float4 anext = *(const float4*)(asrc + (size_t)ktn2 * 32);

    // 3) fragments(kt) from LDS[p]
    half8 af0 = *(const half8*)(Alds[p] + (kb * 64 + wr * 32 +      lr) * 8);
    half8 af1 = *(const half8*)(Alds[p] + (kb * 64 + wr * 32 + 16 + lr) * 8);
    const _Float16* Bp = Blds[p] + (kb * 512 + wc * 128 + lr) * 8;
    half8 bf0 = *(const half8*)(Bp);
    half8 bf1 = *(const half8*)(Bp + 16 * 8);
    half8 bf2 = *(const half8*)(Bp + 32 * 8);
    half8 bf3 = *(const half8*)(Bp + 48 * 8);

    acc[0][0] = __builtin_amdgcn_mfma_f32_16x16x32_f16(af0, bf0, acc[0][0], 0, 0, 0);
    acc[1][0] = __builtin_amdgcn_mfma_f32_16x16x32_f16(af1, bf0, acc[1][0], 0, 0, 0);
    acc[0][1] = __builtin_amdgcn_mfma_f32_16x16x32_f16(af0, bf1, acc[0][1], 0, 0, 0);
    acc[1][1] = __builtin_amdgcn_mfma_f32_16x16x32_f16(af1, bf1, acc[1][1], 0, 0, 0);
    acc[0][2] = __builtin_amdgcn_mfma_f32_16x16x32_f16(af0, bf2, acc[0][2], 0, 0, 0);
    acc[1][2] = __builtin_amdgcn_mfma_f32_16x16x32_f16(af1, bf2, acc[1][2], 0, 0, 0);
    acc[0][3] = __builtin_amdgcn_mfma_f32_16x16x32_f16(af0, bf3, acc[0][3], 0, 0, 0);
    acc[1][3] = __builtin_amdgcn_mfma_f32_16x16x32_f16(af1, bf3, acc[1][3], 0, 0, 0);

    half8 bf4 = *(const half8*)(Bp + 64 * 8);
    half8 bf5 = *(const half8*)(Bp + 80 * 8);
    half8 bf6 = *(const half8*)(Bp + 96 * 8);
    half8 bf7 = *(const half8*)(Bp + 112 * 8);
    acc[0][4] = __builtin_amdgcn_mfma_f32_16x16x32_f16(af0, bf4, acc[0][4], 0, 0, 0);
    acc[1][4] = __builtin_amdgcn_mfma_f32_16x16x32_f16(af1, bf4, acc[1][4], 0, 0, 0);
    acc[0][5] = __builtin_amdgcn_mfma_f32_16x16x32_f16(af0, bf5, acc[0][5], 0, 0, 0);
    acc[1][5] = __builtin_amdgcn_mfma_f32_16x16x32_f16(af1, bf5, acc[1][5], 0, 0, 0);
    acc[0][6] = __builtin_amdgcn_mfma_f32_16x16x32_f16(af0, bf6, acc[0][6], 0, 0, 0);
    acc[1][6] = __builtin_amdgcn_mfma_f32_16x16x32_f16(af1, bf6, acc[1][6], 0, 0, 0);
    acc[0][7] = __builtin_amdgcn_mfma_f32_16x16x32_f16(af0, bf7, acc[0][7], 0, 0, 0);
    acc[1][7] = __builtin_amdgcn_mfma_f32_16x16x32_f16(af1, bf7, acc[1][7], 0, 0, 0);

    // 4) write A(kt+1) (loaded LAST iteration) into buf p^1
    if (kt < 31) {
      half4 h; h[0]=(_Float16)areg.x; h[1]=(_Float16)areg.y; h[2]=(_Float16)areg.z; h[3]=(_Float16)areg.w;
      *(half4*)(Alds[p ^ 1] + awoff) = h;
    }
    __syncthreads();   // drains vmcnt (B gloads) + lgkm (A writes); buf p^1 ready
    p ^= 1;
    areg = anext;
  }

  // ---------------- epilogue (R2-verified mapping, M=64) ----------------
  // C/D: col = lane&15, frag row = kb*4 + j ; global row = wr*32 + m*16 + kb*4 + j
  float sp[2][4];
  #pragma unroll
  for (int m = 0; m < 2; ++m)
    #pragma unroll
    for (int j = 0; j < 4; ++j) sp[m][j] = 0.f;

  #pragma unroll
  for (int n = 0; n < 8; ++n) {
    int col = wc * 128 + n * 16 + lr;
    float wan = wa_s[col], pqn = pq_s[col];
    #pragma unroll
    for (int m = 0; m < 2; ++m)
      #pragma unroll
      for (int j = 0; j < 4; ++j)
        sp[m][j] += fast_tanh(acc[m][n][j] + pqn) * wan;
  }
  #pragma unroll
  for (int m = 0; m < 2; ++m)
    #pragma unroll
    for (int j = 0; j < 4; ++j) {
      float v = sp[m][j];
      v += __shfl_xor(v, 1);
      v += __shfl_xor(v, 2);
      v += __shfl_xor(v, 4);
      v += __shfl_xor(v, 8);
      sp[m][j] = v;
    }
  if (lr == 0) {
    #pragma unroll
    for (int m = 0; m < 2; ++m)
      #pragma unroll
      for (int j = 0; j < 4; ++j)
        sc4[wr * 32 + m * 16 + kb * 4 + j][wc] = sp[m][j];
  }
  __syncthreads();

  const int pi = b * 32 + ch;
  if (tid < 64) {
    float s = sc4[tid][0] + sc4[tid][1] + sc4[tid][2] + sc4[tid][3];
    float mx = s;
    #pragma unroll
    for (int off = 1; off < 64; off <<= 1) mx = fmaxf(mx, __shfl_xor(mx, off));
    float pe = __expf(s - mx);
    float ls = pe;
    #pragma unroll
    for (int off = 1; off < 64; off <<= 1) ls += __shfl_xor(ls, off);
    pbuf[tid] = pe;
    if (tid == 0) { mpart[pi] = mx; lpart[pi] = ls; }
  }
  __syncthreads();

  // ctx partial: sum_s p[s] * proj[s][col]
  float cv[8];
  #pragma unroll
  for (int n = 0; n < 8; ++n) cv[n] = 0.f;
  #pragma unroll
  for (int m = 0; m < 2; ++m)
    #pragma unroll
    for (int j = 0; j < 4; ++j) {
      float pw = pbuf[wr * 32 + m * 16 + kb * 4 + j];
      #pragma unroll
      for (int n = 0; n < 8; ++n) cv[n] += pw * acc[m][n][j];
    }
  #pragma unroll
  for (int n = 0; n < 8; ++n) {
    float v = cv[n];
    v += __shfl_xor(v, 16);
    v += __shfl_xor(v, 32);
    cv[n] = v;                          // sum over this wave's 32 rows
  }
  if (l < 16) {
    #pragma unroll
    for (int n = 0; n < 8; ++n) ctx2[wr][wc * 128 + n * 16 + l] = cv[n];
  }
  __syncthreads();

  ctxp[(size_t)pi * 512 + tid] = ctx2[0][tid] + ctx2[1][tid];
}

// ---- merge 32 chunk partials per batch (flash-style combine)
__global__ void k_comb(const float* __restrict__ mpart, const float* __restrict__ lpart,
                       const float* __restrict__ ctxp, float* __restrict__ out) {
  int b = blockIdx.x, a = threadIdx.x;
  float Mg = -1e30f;
  #pragma unroll 8
  for (int i = 0; i < 32; ++i) Mg = fmaxf(Mg, mpart[b * 32 + i]);
  float den = 0.f, s = 0.f;
  #pragma unroll 8
  for (int i = 0; i < 32; ++i) {
    float e = __expf(mpart[b * 32 + i] - Mg);
    den += lpart[b * 32 + i] * e;
    s   += ctxp[((size_t)(b * 32 + i)) * 512 + a] * e;
  }
  out[(size_t)b * 512 + a] = s / den;
}

extern "C" void kernel_launch(void* const* d_in, const int* in_sizes, int n_in,
                              void* d_out, int out_size, void* d_ws, size_t ws_size,
                              hipStream_t stream) {
  const float* inputs = (const float*)d_in[0];
  const float* query  = (const float*)d_in[1];
  const float* W_in   = (const float*)d_in[2];
  const float* W_q    = (const float*)d_in[3];
  const float* w_att  = (const float*)d_in[4];
  float* out = (float*)d_out;

  char* ws = (char*)d_ws;
  float*    projq = (float*)(ws + WS_PROJQ);
  float*    mpart = (float*)(ws + WS_MPART);
  float*    lpart = (float*)(ws + WS_LPART);
  float*    ctxp  = (float*)(ws + WS_CTXP);
  _Float16* wws   = (_Float16*)(ws + WS_WWS);

  k_convw<<<256, 256, 0, stream>>>(W_in, wws);
  k_projq<<<dim3(8, 32), 256, 0, stream>>>(query, W_q, projq);
  k_main<<<dim3(32, 32), 512, 0, stream>>>(inputs, wws, projq, w_att, mpart, lpart, ctxp);
  k_comb<<<32, 512, 0, stream>>>(mpart, lpart, ctxp, out);
}

// Round 8
// 137.981 us; speedup vs baseline: 1.9557x; 1.4052x over previous
//
#include <hip/hip_runtime.h>
#include <hip/hip_fp16.h>
#include <cstdint>
#include <cstddef>

#define Bb 32
#define Ss 2048
#define Ee 1024
#define Qq 1024
#define Aa 512

typedef _Float16 half8 __attribute__((ext_vector_type(8)));
typedef _Float16 half4 __attribute__((ext_vector_type(4)));
typedef float f32x4 __attribute__((ext_vector_type(4)));

// ---- workspace byte offsets ----
#define WS_PROJQ 0u          // 32*512 f32      = 65536 B
#define WS_MPART 65536u      // 32*16 f32       = 2048 B
#define WS_LPART 67584u      // 32*16 f32       = 2048 B
#define WS_CTXP  69632u      // 32*16*512 f32   = 1048576 B
#define WS_WWS   1118208u    // 1024*512 f16    = 1048576 B

__device__ __forceinline__ float fast_tanh(float x) {
  float e = __expf(2.0f * x);
  return 1.0f - __fdividef(2.0f, e + 1.0f);
}

// ---- W_in fp32 [E][A] -> fp16 tiled [kt][ks][a][8]  (1 MB, L2-resident)
__global__ void k_convw(const float* __restrict__ win, _Float16* __restrict__ wws) {
  int gid = blockIdx.x * 256 + threadIdx.x;
  int a  = gid & 511;
  int ks = (gid >> 9) & 3;
  int kt = gid >> 11;
  int k0 = kt * 32 + ks * 8;
  half8 v;
  #pragma unroll
  for (int j = 0; j < 8; ++j) v[j] = (_Float16)win[(size_t)(k0 + j) * Aa + a];
  *(half8*)(wws + ((size_t)kt * 16384 + (size_t)ks * 4096 + (size_t)a * 8)) = v;
}

// ---- proj_q[b][a]
__global__ void k_projq(const float* __restrict__ query, const float* __restrict__ wq,
                        float* __restrict__ projq) {
  __shared__ float red[256];
  int b  = blockIdx.y;
  int al = threadIdx.x & 63;
  int eq = threadIdx.x >> 6;
  int a  = blockIdx.x * 64 + al;
  const float* q = query + (size_t)b * Qq;
  float s = 0.f;
  int e0 = eq * 256;
  #pragma unroll 4
  for (int e = e0; e < e0 + 256; ++e)
    s += q[e] * wq[(size_t)e * Aa + a];
  red[threadIdx.x] = s;
  __syncthreads();
  if (eq == 0)
    projq[(size_t)b * Aa + a] = red[al] + red[al + 64] + red[al + 128] + red[al + 192];
}

// ---- main: BM=128 x BN=512, BK=32, 1024 threads (16 waves = 4wr x 4wc).
// Per kt per SIMD: 4 waves x 16 MFMA (~1240 cyc issue) >> drain (~300) -> lockstep ok.
// B: global_load_lds 2x16B/thread into 32KB dbuf (R7-verified pattern).
// A: reg-staged f32->f16 depth-2 (R7-verified). 512 blocks -> 2 rounds/CU.
__global__ __launch_bounds__(1024, 4)
void k_main(const float* __restrict__ inp, const _Float16* __restrict__ wws,
            const float* __restrict__ projq, const float* __restrict__ watt,
            float* __restrict__ mpart, float* __restrict__ lpart,
            float* __restrict__ ctxp)
{
  __shared__ __align__(16) _Float16 Alds[2][4 * 128 * 8];   // [p][ks][row128][8] 2x8KB
  __shared__ __align__(16) _Float16 Blds[2][4 * 512 * 8];   // [p][ks][a][8]      2x32KB
  __shared__ float pq_s[512];
  __shared__ float wa_s[512];
  __shared__ float sc4[128][4];
  __shared__ float pbuf[128];
  __shared__ float red2[8];
  __shared__ float ctx2[4][512];

  const int tid = threadIdx.x;
  const int l   = tid & 63;
  const int w   = tid >> 6;        // wave 0..15
  const int lr  = l & 15;
  const int kb  = l >> 4;          // k-slot 0..3
  const int wr  = w >> 2;          // m-quarter 0..3 (rows wr*32..+31)
  const int wc  = w & 3;           // n-slice 0..3 (cols wc*128..+127)
  const int b   = blockIdx.y;
  const int ch  = blockIdx.x;      // s-chunk of 128 rows, 0..15

  if (tid < 512) {
    pq_s[tid] = projq[(size_t)b * Aa + tid];
    wa_s[tid] = watt[tid];
  }

  // A staging: thread t -> row = t>>3 (0..127), kq = t&7 (float4 group)
  const int arow = tid >> 3;
  const int kq   = tid & 7;
  const float* asrc = inp + ((size_t)(b * Ss + ch * 128 + arow)) * Ee + kq * 4;
  const int awoff = ((kq >> 1) * 128 + arow) * 8 + (kq & 1) * 4;   // f16 elem offset

  // B staging: 2 x 16B per thread, linear (tid*16 + i*16384 covers 32KB/kt)
  const char* bsrc0 = (const char*)wws + (size_t)tid * 16;

  f32x4 acc[2][8];
  #pragma unroll
  for (int m = 0; m < 2; ++m)
    #pragma unroll
    for (int n = 0; n < 8; ++n) acc[m][n] = (f32x4){0.f, 0.f, 0.f, 0.f};

  // ---- prologue: stage kt=0 into buf 0; preload A(1)
  {
    float4 x = *(const float4*)(asrc);              // A(0)
    half4 h; h[0]=(_Float16)x.x; h[1]=(_Float16)x.y; h[2]=(_Float16)x.z; h[3]=(_Float16)x.w;
    *(half4*)(Alds[0] + awoff) = h;
    #pragma unroll
    for (int i = 0; i < 2; ++i)
      __builtin_amdgcn_global_load_lds(
        (const __attribute__((address_space(1))) void*)(bsrc0 + i * 16384),
        (__attribute__((address_space(3))) void*)((char*)Blds[0] + tid * 16 + i * 16384),
        16, 0, 0);
  }
  float4 areg = *(const float4*)(asrc + 32);        // A(1)
  __syncthreads();

  int p = 0;
  for (int kt = 0; kt < 32; ++kt) {
    // 1) issue B(kt+1) gloads into buf p^1 (whole MFMA phase to land)
    if (kt < 31) {
      const char* bs = bsrc0 + (size_t)(kt + 1) * 32768;
      #pragma unroll
      for (int i = 0; i < 2; ++i)
        __builtin_amdgcn_global_load_lds(
          (const __attribute__((address_space(1))) void*)(bs + i * 16384),
          (__attribute__((address_space(3))) void*)((char*)Blds[p ^ 1] + tid * 16 + i * 16384),
          16, 0, 0);
    }
    // 2) A(kt+2) into regs (consumed NEXT iteration -> ~1 full kt of cover)
    const int ktn2 = (kt < 30) ? kt + 2 : 31;
    float4 anext = *(const float4*)(asrc + (size_t)ktn2 * 32);

    // 3) fragments(kt) from LDS[p]
    half8 af0 = *(const half8*)(Alds[p] + (kb * 128 + wr * 32 +      lr) * 8);
    half8 af1 = *(const half8*)(Alds[p] + (kb * 128 + wr * 32 + 16 + lr) * 8);
    const _Float16* Bp = Blds[p] + (kb * 512 + wc * 128 + lr) * 8;
    half8 bf0 = *(const half8*)(Bp);
    half8 bf1 = *(const half8*)(Bp + 16 * 8);
    half8 bf2 = *(const half8*)(Bp + 32 * 8);
    half8 bf3 = *(const half8*)(Bp + 48 * 8);

    acc[0][0] = __builtin_amdgcn_mfma_f32_16x16x32_f16(af0, bf0, acc[0][0], 0, 0, 0);
    acc[1][0] = __builtin_amdgcn_mfma_f32_16x16x32_f16(af1, bf0, acc[1][0], 0, 0, 0);
    acc[0][1] = __builtin_amdgcn_mfma_f32_16x16x32_f16(af0, bf1, acc[0][1], 0, 0, 0);
    acc[1][1] = __builtin_amdgcn_mfma_f32_16x16x32_f16(af1, bf1, acc[1][1], 0, 0, 0);
    acc[0][2] = __builtin_amdgcn_mfma_f32_16x16x32_f16(af0, bf2, acc[0][2], 0, 0, 0);
    acc[1][2] = __builtin_amdgcn_mfma_f32_16x16x32_f16(af1, bf2, acc[1][2], 0, 0, 0);
    acc[0][3] = __builtin_amdgcn_mfma_f32_16x16x32_f16(af0, bf3, acc[0][3], 0, 0, 0);
    acc[1][3] = __builtin_amdgcn_mfma_f32_16x16x32_f16(af1, bf3, acc[1][3], 0, 0, 0);

    half8 bf4 = *(const half8*)(Bp + 64 * 8);
    half8 bf5 = *(const half8*)(Bp + 80 * 8);
    half8 bf6 = *(const half8*)(Bp + 96 * 8);
    half8 bf7 = *(const half8*)(Bp + 112 * 8);
    acc[0][4] = __builtin_amdgcn_mfma_f32_16x16x32_f16(af0, bf4, acc[0][4], 0, 0, 0);
    acc[1][4] = __builtin_amdgcn_mfma_f32_16x16x32_f16(af1, bf4, acc[1][4], 0, 0, 0);
    acc[0][5] = __builtin_amdgcn_mfma_f32_16x16x32_f16(af0, bf5, acc[0][5], 0, 0, 0);
    acc[1][5] = __builtin_amdgcn_mfma_f32_16x16x32_f16(af1, bf5, acc[1][5], 0, 0, 0);
    acc[0][6] = __builtin_amdgcn_mfma_f32_16x16x32_f16(af0, bf6, acc[0][6], 0, 0, 0);
    acc[1][6] = __builtin_amdgcn_mfma_f32_16x16x32_f16(af1, bf6, acc[1][6], 0, 0, 0);
    acc[0][7] = __builtin_amdgcn_mfma_f32_16x16x32_f16(af0, bf7, acc[0][7], 0, 0, 0);
    acc[1][7] = __builtin_amdgcn_mfma_f32_16x16x32_f16(af1, bf7, acc[1][7], 0, 0, 0);

    // 4) write A(kt+1) (loaded LAST iteration) into buf p^1
    if (kt < 31) {
      half4 h; h[0]=(_Float16)areg.x; h[1]=(_Float16)areg.y; h[2]=(_Float16)areg.z; h[3]=(_Float16)areg.w;
      *(half4*)(Alds[p ^ 1] + awoff) = h;
    }
    __syncthreads();
    p ^= 1;
    areg = anext;
  }

  // ---------------- epilogue (R7-verified mapping, wr in 0..3) ----------------
  // C/D: col = lane&15, frag row = kb*4 + j ; global row = wr*32 + m*16 + kb*4 + j
  float sp[2][4];
  #pragma unroll
  for (int m = 0; m < 2; ++m)
    #pragma unroll
    for (int j = 0; j < 4; ++j) sp[m][j] = 0.f;

  #pragma unroll
  for (int n = 0; n < 8; ++n) {
    int col = wc * 128 + n * 16 + lr;
    float wan = wa_s[col], pqn = pq_s[col];
    #pragma unroll
    for (int m = 0; m < 2; ++m)
      #pragma unroll
      for (int j = 0; j < 4; ++j)
        sp[m][j] += fast_tanh(acc[m][n][j] + pqn) * wan;
  }
  #pragma unroll
  for (int m = 0; m < 2; ++m)
    #pragma unroll
    for (int j = 0; j < 4; ++j) {
      float v = sp[m][j];
      v += __shfl_xor(v, 1);
      v += __shfl_xor(v, 2);
      v += __shfl_xor(v, 4);
      v += __shfl_xor(v, 8);
      sp[m][j] = v;                    // reduced over this wave's 16-col group
    }
  if (lr == 0) {
    #pragma unroll
    for (int m = 0; m < 2; ++m)
      #pragma unroll
      for (int j = 0; j < 4; ++j)
        sc4[wr * 32 + m * 16 + kb * 4 + j][wc] = sp[m][j];
  }
  __syncthreads();

  // row scores (128 rows handled by waves 0 and 1), two-level max/sum
  const int pi = b * 16 + ch;
  float s = 0.f, pe = 0.f;
  if (tid < 128) {
    s = sc4[tid][0] + sc4[tid][1] + sc4[tid][2] + sc4[tid][3];
    float mx = s;
    #pragma unroll
    for (int off = 1; off < 64; off <<= 1) mx = fmaxf(mx, __shfl_xor(mx, off));
    if (l == 0) red2[w] = mx;
  }
  __syncthreads();
  float Mx = fmaxf(red2[0], red2[1]);
  if (tid < 128) {
    pe = __expf(s - Mx);
    pbuf[tid] = pe;
    float ls = pe;
    #pragma unroll
    for (int off = 1; off < 64; off <<= 1) ls += __shfl_xor(ls, off);
    if (l == 0) red2[4 + w] = ls;
  }
  __syncthreads();
  if (tid == 0) { mpart[pi] = Mx; lpart[pi] = red2[4] + red2[5]; }

  // ctx partial: sum_s p[s] * proj[s][col]
  float cv[8];
  #pragma unroll
  for (int n = 0; n < 8; ++n) cv[n] = 0.f;
  #pragma unroll
  for (int m = 0; m < 2; ++m)
    #pragma unroll
    for (int j = 0; j < 4; ++j) {
      float pw = pbuf[wr * 32 + m * 16 + kb * 4 + j];
      #pragma unroll
      for (int n = 0; n < 8; ++n) cv[n] += pw * acc[m][n][j];
    }
  #pragma unroll
  for (int n = 0; n < 8; ++n) {
    float v = cv[n];
    v += __shfl_xor(v, 16);
    v += __shfl_xor(v, 32);
    cv[n] = v;                         // sum over this wave's 32 rows
  }
  if (l < 16) {
    #pragma unroll
    for (int n = 0; n < 8; ++n) ctx2[wr][wc * 128 + n * 16 + l] = cv[n];
  }
  __syncthreads();

  if (tid < 512)
    ctxp[(size_t)pi * 512 + tid] =
        ctx2[0][tid] + ctx2[1][tid] + ctx2[2][tid] + ctx2[3][tid];
}

// ---- merge 16 chunk partials per batch (flash-style combine)
__global__ void k_comb(const float* __restrict__ mpart, const float* __restrict__ lpart,
                       const float* __restrict__ ctxp, float* __restrict__ out) {
  int b = blockIdx.x, a = threadIdx.x;
  float Mg = -1e30f;
  #pragma unroll
  for (int i = 0; i < 16; ++i) Mg = fmaxf(Mg, mpart[b * 16 + i]);
  float den = 0.f, s = 0.f;
  #pragma unroll
  for (int i = 0; i < 16; ++i) {
    float e = __expf(mpart[b * 16 + i] - Mg);
    den += lpart[b * 16 + i] * e;
    s   += ctxp[((size_t)(b * 16 + i)) * 512 + a] * e;
  }
  out[(size_t)b * 512 + a] = s / den;
}

extern "C" void kernel_launch(void* const* d_in, const int* in_sizes, int n_in,
                              void* d_out, int out_size, void* d_ws, size_t ws_size,
                              hipStream_t stream) {
  const float* inputs = (const float*)d_in[0];
  const float* query  = (const float*)d_in[1];
  const float* W_in   = (const float*)d_in[2];
  const float* W_q    = (const float*)d_in[3];
  const float* w_att  = (const float*)d_in[4];
  float* out = (float*)d_out;

  char* ws = (char*)d_ws;
  float*    projq = (float*)(ws + WS_PROJQ);
  float*    mpart = (float*)(ws + WS_MPART);
  float*    lpart = (float*)(ws + WS_LPART);
  float*    ctxp  = (float*)(ws + WS_CTXP);
  _Float16* wws   = (_Float16*)(ws + WS_WWS);

  k_convw<<<256, 256, 0, stream>>>(W_in, wws);
  k_projq<<<dim3(8, 32), 256, 0, stream>>>(query, W_q, projq);
  k_main<<<dim3(16, 32), 1024, 0, stream>>>(inputs, wws, projq, w_att, mpart, lpart, ctxp);
  k_comb<<<32, 512, 0, stream>>>(mpart, lpart, ctxp, out);
}